// Round 4
// baseline (69.121 us; speedup 1.0000x reference)
//
#include <hip/hip_runtime.h>

typedef __bf16 bf16x8 __attribute__((ext_vector_type(8)));
typedef float f32x16 __attribute__((ext_vector_type(16)));

constexpr int S = 128, R = 256, CM = 256, C = 32, CZ = 128;

#define MFMA __builtin_amdgcn_mfma_f32_32x32x16_bf16

__device__ __forceinline__ unsigned short f32_to_bf16(float f) {
    unsigned int u = __builtin_bit_cast(unsigned int, f);
    u += 0x7FFFu + ((u >> 16) & 1u);
    return (unsigned short)(u >> 16);
}

// K0a: fragment-packed out_proj. k = e*32+c (phase-B K index), frag f = k>>3,
// WTf[((k>>3)*128 + cz)*8 + (k&7)] = W[(c*32+e)*128+cz]
__global__ __launch_bounds__(256) void k_wt(const float* __restrict__ W,
                                            unsigned short* __restrict__ WTf) {
    int g = blockIdx.x * 256 + threadIdx.x;
    int cz = g & 127;
    int k = g >> 7;
    int e = k >> 5, c = k & 31;
    float v = W[(size_t)(c * 32 + e) * 128 + cz];
    WTf[((size_t)(k >> 3) * 128 + cz) * 8 + (k & 7)] = f32_to_bf16(v);
}

// K0b: WLRT[c][m], c in [0,64): c<32 -> left[m][c], else right[m][c-32]
__global__ __launch_bounds__(256) void k_wlr(const float* __restrict__ Lp,
                                             const float* __restrict__ Rp,
                                             unsigned short* __restrict__ WLRT) {
    int c = blockIdx.x;
    int m = threadIdx.x;
    const float* src = (c < 32) ? Lp : Rp;
    WLRT[(size_t)c * 256 + m] = f32_to_bf16(src[(size_t)m * 32 + (c & 31)]);
}

// K1 (MFMA): per block one r. Writes fragment-packed aTf/bTf[r][ks][khf][c][8s]
__global__ __launch_bounds__(256) void k_proj(const float* __restrict__ msa,
                                              const unsigned short* __restrict__ WLRT,
                                              unsigned short* __restrict__ aTf,
                                              unsigned short* __restrict__ bTf) {
    __shared__ __align__(16) unsigned short As[128 * 256];
    const int r = blockIdx.x;
    const int t = threadIdx.x;
    const int w = t >> 6;
    const int lane = t & 63;

#pragma unroll 4
    for (int it = 0; it < 32; ++it) {
        int row = it * 4 + w;
        float4 v = *(const float4*)&msa[((size_t)row * R + r) * CM + lane * 4];
        ushort4 h;
        h.x = f32_to_bf16(v.x); h.y = f32_to_bf16(v.y);
        h.z = f32_to_bf16(v.z); h.w = f32_to_bf16(v.w);
        int P = (lane >> 1) ^ (row & 15);
        *(ushort4*)((char*)As + row * 512 + P * 16 + (lane & 1) * 8) = h;
    }
    __syncthreads();

    const int l31 = t & 31;
    const int kh = (t >> 5) & 1;
    f32x16 accL, accR;
#pragma unroll
    for (int q = 0; q < 16; ++q) { accL[q] = 0.f; accR[q] = 0.f; }

    const bf16x8* wbL = (const bf16x8*)&WLRT[(size_t)l31 * 256 + 8 * kh];
    const bf16x8* wbR = (const bf16x8*)&WLRT[(size_t)(32 + l31) * 256 + 8 * kh];
    const int srow = w * 32 + l31;
    const char* arow = (const char*)As + srow * 512;

    __builtin_amdgcn_s_setprio(1);
#pragma unroll
    for (int ks = 0; ks < 16; ++ks) {
        int P = (2 * ks + kh) ^ (srow & 15);
        bf16x8 af = *(const bf16x8*)(arow + P * 16);
        accL = MFMA(af, wbL[2 * ks], accL, 0, 0, 0);
        accR = MFMA(af, wbR[2 * ks], accR, 0, 0, 0);
    }
    __builtin_amdgcn_s_setprio(0);

#pragma unroll
    for (int q = 0; q < 4; ++q) {
        size_t base = (size_t)r * 4096 + (size_t)(2 * w + (q >> 1)) * 512 +
                      (size_t)(q & 1) * 256 + (size_t)l31 * 8 + 4 * kh;
        ushort4 ha, hb;
        ha.x = f32_to_bf16(accL[4 * q + 0]); ha.y = f32_to_bf16(accL[4 * q + 1]);
        ha.z = f32_to_bf16(accL[4 * q + 2]); ha.w = f32_to_bf16(accL[4 * q + 3]);
        hb.x = f32_to_bf16(accR[4 * q + 0]); hb.y = f32_to_bf16(accR[4 * q + 1]);
        hb.z = f32_to_bf16(accR[4 * q + 2]); hb.w = f32_to_bf16(accR[4 * q + 3]);
        *(ushort4*)&aTf[base] = ha;
        *(ushort4*)&bTf[base] = hb;
    }
}

// K2: 64 pairs (8r x 8t) per block, 8 waves / 512 threads, G in 128 KB LDS.
// Phase A: wave (wr=w&3, wt=w>>2) computes 2r x 4t sub-tile.
// Phase B: wave (mt=w>>2, ns=w&3) does M-tile of 32 pairs x 32-cz slice.
__global__ __launch_bounds__(512, 2) void k_main(const unsigned short* __restrict__ aTf,
                                                 const unsigned short* __restrict__ bTf,
                                                 const unsigned short* __restrict__ WTf,
                                                 float* __restrict__ out) {
    __shared__ __align__(16) unsigned short Gs[64 * 1024];   // 128 KB

    const int t = threadIdx.x;
    const int w = t >> 6;           // 0..7
    const int l = t & 63;
    const int lane = l & 31;
    const int kh = l >> 5;
    const int r0 = blockIdx.x * 8;
    const int t0 = blockIdx.y * 8;

    // ---------------- Phase A ----------------
    const int wr = w & 3;           // r sub-group
    const int wt = w >> 2;          // t sub-group
    const int ri0 = 2 * wr;
    const int tj0 = 4 * wt;

    f32x16 acc[2][4];
#pragma unroll
    for (int i = 0; i < 2; ++i)
#pragma unroll
        for (int j = 0; j < 4; ++j)
#pragma unroll
            for (int q = 0; q < 16; ++q) acc[i][j][q] = 0.f;

    const bf16x8* ap0 = (const bf16x8*)aTf + ((size_t)(r0 + ri0 + 0) * 512 + kh * 32 + lane);
    const bf16x8* ap1 = (const bf16x8*)aTf + ((size_t)(r0 + ri0 + 1) * 512 + kh * 32 + lane);
    const bf16x8* bp0 = (const bf16x8*)bTf + ((size_t)(t0 + tj0 + 0) * 512 + kh * 32 + lane);
    const bf16x8* bp1 = (const bf16x8*)bTf + ((size_t)(t0 + tj0 + 1) * 512 + kh * 32 + lane);
    const bf16x8* bp2 = (const bf16x8*)bTf + ((size_t)(t0 + tj0 + 2) * 512 + kh * 32 + lane);
    const bf16x8* bp3 = (const bf16x8*)bTf + ((size_t)(t0 + tj0 + 3) * 512 + kh * 32 + lane);

    bf16x8 A0[2], B0[4], A1[2], B1[4];
#define LDA(Aa, Bb, ks) do { \
    Aa[0] = ap0[(ks) * 64]; Aa[1] = ap1[(ks) * 64]; \
    Bb[0] = bp0[(ks) * 64]; Bb[1] = bp1[(ks) * 64]; \
    Bb[2] = bp2[(ks) * 64]; Bb[3] = bp3[(ks) * 64]; } while (0)
#define PH_A(Aa, Bb) do { \
    __builtin_amdgcn_s_setprio(1); \
    acc[0][0] = MFMA(Aa[0], Bb[0], acc[0][0], 0, 0, 0); \
    acc[0][1] = MFMA(Aa[0], Bb[1], acc[0][1], 0, 0, 0); \
    acc[0][2] = MFMA(Aa[0], Bb[2], acc[0][2], 0, 0, 0); \
    acc[0][3] = MFMA(Aa[0], Bb[3], acc[0][3], 0, 0, 0); \
    acc[1][0] = MFMA(Aa[1], Bb[0], acc[1][0], 0, 0, 0); \
    acc[1][1] = MFMA(Aa[1], Bb[1], acc[1][1], 0, 0, 0); \
    acc[1][2] = MFMA(Aa[1], Bb[2], acc[1][2], 0, 0, 0); \
    acc[1][3] = MFMA(Aa[1], Bb[3], acc[1][3], 0, 0, 0); \
    __builtin_amdgcn_s_setprio(0); } while (0)

    LDA(A0, B0, 0);
#pragma unroll
    for (int ks = 0; ks < 8; ks += 2) {
        LDA(A1, B1, ks + 1);
        PH_A(A0, B0);
        LDA(A0, B0, (ks + 2) & 7);
        PH_A(A1, B1);
    }

    // G -> LDS bf16, row p = ri*8 + tj (2048 B each), chunk swizzle
#pragma unroll
    for (int i = 0; i < 2; ++i) {
#pragma unroll
        for (int j = 0; j < 4; ++j) {
            int p = (ri0 + i) * 8 + tj0 + j;
            unsigned prow = (unsigned)p * 2048;
#pragma unroll
            for (int q = 0; q < 4; ++q) {
                int Lc = lane * 4 + q;
                int P = Lc ^ (p & 15) ^ (lane & 7);
                ushort4 hv;
                hv.x = f32_to_bf16(acc[i][j][4 * q + 0]);
                hv.y = f32_to_bf16(acc[i][j][4 * q + 1]);
                hv.z = f32_to_bf16(acc[i][j][4 * q + 2]);
                hv.w = f32_to_bf16(acc[i][j][4 * q + 3]);
                *(ushort4*)((char*)Gs + prow + (unsigned)P * 16 + kh * 8) = hv;
            }
        }
    }
    __syncthreads();

    // ---------------- Phase B ----------------
    const int mt = w >> 2;          // M-tile (pairs 32*mt ..)
    const int ns = w & 3;           // cz slice
    f32x16 oA, oB;
#pragma unroll
    for (int q = 0; q < 16; ++q) { oA[q] = 0.f; oB[q] = 0.f; }

    const int czl = ns * 32 + lane;
    const bf16x8* wb = (const bf16x8*)WTf + ((size_t)kh * 128 + czl);
    const unsigned prow = (unsigned)(mt * 32 + lane) * 2048;
    const int p15 = lane & 15;

#define LDG(dst, kk) do { \
    int Lr = (kk) * 2 + kh; \
    int P = Lr ^ p15 ^ ((Lr >> 2) & 7); \
    dst = *(const bf16x8*)((const char*)Gs + prow + (unsigned)P * 16); } while (0)

    bf16x8 G0[8], W0[8], G1[8], W1[8];
#define LD8(Gg, Ww, kb) do { \
    LDG(Gg[0], (kb) + 0); LDG(Gg[1], (kb) + 1); LDG(Gg[2], (kb) + 2); LDG(Gg[3], (kb) + 3); \
    LDG(Gg[4], (kb) + 4); LDG(Gg[5], (kb) + 5); LDG(Gg[6], (kb) + 6); LDG(Gg[7], (kb) + 7); \
    Ww[0] = wb[((kb) + 0) * 256]; Ww[1] = wb[((kb) + 1) * 256]; \
    Ww[2] = wb[((kb) + 2) * 256]; Ww[3] = wb[((kb) + 3) * 256]; \
    Ww[4] = wb[((kb) + 4) * 256]; Ww[5] = wb[((kb) + 5) * 256]; \
    Ww[6] = wb[((kb) + 6) * 256]; Ww[7] = wb[((kb) + 7) * 256]; } while (0)

#define PH_B(Gg, Ww) do { \
    __builtin_amdgcn_s_setprio(1); \
    oA = MFMA(Gg[0], Ww[0], oA, 0, 0, 0); oB = MFMA(Gg[1], Ww[1], oB, 0, 0, 0); \
    oA = MFMA(Gg[2], Ww[2], oA, 0, 0, 0); oB = MFMA(Gg[3], Ww[3], oB, 0, 0, 0); \
    oA = MFMA(Gg[4], Ww[4], oA, 0, 0, 0); oB = MFMA(Gg[5], Ww[5], oB, 0, 0, 0); \
    oA = MFMA(Gg[6], Ww[6], oA, 0, 0, 0); oB = MFMA(Gg[7], Ww[7], oB, 0, 0, 0); \
    __builtin_amdgcn_s_setprio(0); } while (0)

    LD8(G0, W0, 0);
#pragma unroll
    for (int kk = 0; kk < 64; kk += 16) {
        LD8(G1, W1, kk + 8);
        PH_B(G0, W0);
        LD8(G0, W0, (kk + 16) & 63);
        PH_B(G1, W1);
    }
    f32x16 o = oA + oB;

    // D rows -> pair = mt*32 + (reg&3) + 8*(reg>>2) + 4*kh; pr = pair>>3, pt = pair&7
#pragma unroll
    for (int reg = 0; reg < 16; ++reg) {
        int pl = (reg & 3) + 8 * (reg >> 2) + 4 * kh;
        int pair = mt * 32 + pl;
        int pr = pair >> 3, pt = pair & 7;
        out[((size_t)(r0 + pr) * 256 + (t0 + pt)) * 128 + czl] = o[reg];
    }
}

extern "C" void kernel_launch(void* const* d_in, const int* in_sizes, int n_in,
                              void* d_out, int out_size, void* d_ws, size_t ws_size,
                              hipStream_t stream) {
    const float* msa = (const float*)d_in[0];
    const float* left = (const float*)d_in[1];
    const float* right = (const float*)d_in[2];
    const float* W = (const float*)d_in[3];

    unsigned short* aTf = (unsigned short*)d_ws;                // 2 MB
    unsigned short* bTf = aTf + (size_t)R * 4096;               // 2 MB
    unsigned short* WTf = bTf + (size_t)R * 4096;               // 256 KB
    unsigned short* WLRT = WTf + (size_t)128 * 1024;            // 32 KB
    float* outp = (float*)d_out;

    k_wt<<<512, 256, 0, stream>>>(W, WTf);
    k_wlr<<<64, 256, 0, stream>>>(left, right, WLRT);
    k_proj<<<256, 256, 0, stream>>>(msa, WLRT, aTf, bTf);
    k_main<<<dim3(32, 32), 512, 0, stream>>>(aTf, bTf, WTf, outp);
}

// Round 6
// 67.196 us; speedup vs baseline: 1.0286x; 1.0286x over previous
//
#include <hip/hip_runtime.h>

typedef __bf16 bf16x8 __attribute__((ext_vector_type(8)));
typedef __bf16 bf16x4 __attribute__((ext_vector_type(4)));
typedef float f32x16 __attribute__((ext_vector_type(16)));

constexpr int S = 128, R = 256, CM = 256, C = 32, CZ = 128;

#define MFMA __builtin_amdgcn_mfma_f32_32x32x16_bf16

__device__ __forceinline__ bf16x4 cvt4(float a, float b, float c, float d) {
    bf16x4 r;
    r[0] = (__bf16)a; r[1] = (__bf16)b; r[2] = (__bf16)c; r[3] = (__bf16)d;
    return r;
}

// K0a: fragment-packed out_proj. k = e*32+c (phase-B K index), frag f = k>>3,
// WTf[((k>>3)*128 + cz)*8 + (k&7)] = W[(c*32+e)*128+cz]
__global__ __launch_bounds__(256) void k_wt(const float* __restrict__ W,
                                            __bf16* __restrict__ WTf) {
    int g = blockIdx.x * 256 + threadIdx.x;
    int cz = g & 127;
    int k = g >> 7;
    int e = k >> 5, c = k & 31;
    float v = W[(size_t)(c * 32 + e) * 128 + cz];
    WTf[((size_t)(k >> 3) * 128 + cz) * 8 + (k & 7)] = (__bf16)v;
}

// K0b: WLRT[c][m], c in [0,64): c<32 -> left[m][c], else right[m][c-32]
__global__ __launch_bounds__(256) void k_wlr(const float* __restrict__ Lp,
                                             const float* __restrict__ Rp,
                                             __bf16* __restrict__ WLRT) {
    int c = blockIdx.x;
    int m = threadIdx.x;
    const float* src = (c < 32) ? Lp : Rp;
    WLRT[(size_t)c * 256 + m] = (__bf16)src[(size_t)m * 32 + (c & 31)];
}

// K1 (MFMA): per block one r. Writes fragment-packed aTf/bTf[r][ks][khf][c][8s]
__global__ __launch_bounds__(256) void k_proj(const float* __restrict__ msa,
                                              const __bf16* __restrict__ WLRT,
                                              __bf16* __restrict__ aTf,
                                              __bf16* __restrict__ bTf) {
    __shared__ __align__(16) __bf16 As[128 * 256];
    const int r = blockIdx.x;
    const int t = threadIdx.x;
    const int w = t >> 6;
    const int lane = t & 63;

#pragma unroll 4
    for (int it = 0; it < 32; ++it) {
        int row = it * 4 + w;
        float4 v = *(const float4*)&msa[((size_t)row * R + r) * CM + lane * 4];
        bf16x4 h = cvt4(v.x, v.y, v.z, v.w);
        int P = (lane >> 1) ^ (row & 15);
        *(bf16x4*)((char*)As + row * 512 + P * 16 + (lane & 1) * 8) = h;
    }
    __syncthreads();

    const int l31 = t & 31;
    const int kh = (t >> 5) & 1;
    f32x16 accL, accR;
#pragma unroll
    for (int q = 0; q < 16; ++q) { accL[q] = 0.f; accR[q] = 0.f; }

    const bf16x8* wbL = (const bf16x8*)&WLRT[(size_t)l31 * 256 + 8 * kh];
    const bf16x8* wbR = (const bf16x8*)&WLRT[(size_t)(32 + l31) * 256 + 8 * kh];
    const int srow = w * 32 + l31;
    const char* arow = (const char*)As + srow * 512;

    __builtin_amdgcn_s_setprio(1);
#pragma unroll
    for (int ks = 0; ks < 16; ++ks) {
        int P = (2 * ks + kh) ^ (srow & 15);
        bf16x8 af = *(const bf16x8*)(arow + P * 16);
        accL = MFMA(af, wbL[2 * ks], accL, 0, 0, 0);
        accR = MFMA(af, wbR[2 * ks], accR, 0, 0, 0);
    }
    __builtin_amdgcn_s_setprio(0);

#pragma unroll
    for (int q = 0; q < 4; ++q) {
        size_t base = (size_t)r * 4096 + (size_t)(2 * w + (q >> 1)) * 512 +
                      (size_t)(q & 1) * 256 + (size_t)l31 * 8 + 4 * kh;
        *(bf16x4*)&aTf[base] = cvt4(accL[4 * q + 0], accL[4 * q + 1],
                                    accL[4 * q + 2], accL[4 * q + 3]);
        *(bf16x4*)&bTf[base] = cvt4(accR[4 * q + 0], accR[4 * q + 1],
                                    accR[4 * q + 2], accR[4 * q + 3]);
    }
}

// K2: 32 pairs (8r x 4t) per block, 4 waves, 64 KB LDS, 2 blocks/CU.
// Phase A depth-3 prefetch; phase B: W depth-3, G depth-2 (all hand-unrolled).
__global__ __launch_bounds__(256, 2) void k_main(const __bf16* __restrict__ aTf,
                                                 const __bf16* __restrict__ bTf,
                                                 const __bf16* __restrict__ WTf,
                                                 float* __restrict__ out) {
    __shared__ __align__(16) __bf16 Gs[32 * 1024];   // 64 KB

    const int t = threadIdx.x;
    const int w = t >> 6;
    const int l = t & 63;
    const int lane = l & 31;
    const int kh = l >> 5;
    const int r0 = blockIdx.x * 8;
    const int t0 = blockIdx.y * 4;

    // ---------------- Phase A ----------------
    f32x16 acc[2][4];
#pragma unroll
    for (int i = 0; i < 2; ++i)
#pragma unroll
        for (int j = 0; j < 4; ++j)
#pragma unroll
            for (int q = 0; q < 16; ++q) acc[i][j][q] = 0.f;

    const bf16x8* ap0 = (const bf16x8*)aTf + ((size_t)(r0 + 2 * w + 0) * 512 + kh * 32 + lane);
    const bf16x8* ap1 = (const bf16x8*)aTf + ((size_t)(r0 + 2 * w + 1) * 512 + kh * 32 + lane);
    const bf16x8* bp0 = (const bf16x8*)bTf + ((size_t)(t0 + 0) * 512 + kh * 32 + lane);
    const bf16x8* bp1 = (const bf16x8*)bTf + ((size_t)(t0 + 1) * 512 + kh * 32 + lane);
    const bf16x8* bp2 = (const bf16x8*)bTf + ((size_t)(t0 + 2) * 512 + kh * 32 + lane);
    const bf16x8* bp3 = (const bf16x8*)bTf + ((size_t)(t0 + 3) * 512 + kh * 32 + lane);

    bf16x8 A0[2], B0[4], A1[2], B1[4], A2[2], B2[4];
#define LDA(Aa, Bb, ks) do { \
    Aa[0] = ap0[(ks) * 64]; Aa[1] = ap1[(ks) * 64]; \
    Bb[0] = bp0[(ks) * 64]; Bb[1] = bp1[(ks) * 64]; \
    Bb[2] = bp2[(ks) * 64]; Bb[3] = bp3[(ks) * 64]; } while (0)
#define PH_A(Aa, Bb) do { \
    __builtin_amdgcn_s_setprio(1); \
    acc[0][0] = MFMA(Aa[0], Bb[0], acc[0][0], 0, 0, 0); \
    acc[0][1] = MFMA(Aa[0], Bb[1], acc[0][1], 0, 0, 0); \
    acc[0][2] = MFMA(Aa[0], Bb[2], acc[0][2], 0, 0, 0); \
    acc[0][3] = MFMA(Aa[0], Bb[3], acc[0][3], 0, 0, 0); \
    acc[1][0] = MFMA(Aa[1], Bb[0], acc[1][0], 0, 0, 0); \
    acc[1][1] = MFMA(Aa[1], Bb[1], acc[1][1], 0, 0, 0); \
    acc[1][2] = MFMA(Aa[1], Bb[2], acc[1][2], 0, 0, 0); \
    acc[1][3] = MFMA(Aa[1], Bb[3], acc[1][3], 0, 0, 0); \
    __builtin_amdgcn_s_setprio(0); } while (0)

    LDA(A0, B0, 0); LDA(A1, B1, 1); LDA(A2, B2, 2);
    PH_A(A0, B0); LDA(A0, B0, 3);
    PH_A(A1, B1); LDA(A1, B1, 4);
    PH_A(A2, B2); LDA(A2, B2, 5);
    PH_A(A0, B0); LDA(A0, B0, 6);
    PH_A(A1, B1); LDA(A1, B1, 7);
    PH_A(A2, B2);
    PH_A(A0, B0);
    PH_A(A1, B1);

    // G -> LDS bf16, row p (2048 B), chunk swizzle P = L ^ (p&15) ^ ((L>>2)&7)
#pragma unroll
    for (int i = 0; i < 2; ++i) {
#pragma unroll
        for (int j = 0; j < 4; ++j) {
            int p = (2 * w + i) * 4 + j;
            unsigned prow = (unsigned)p * 2048;
#pragma unroll
            for (int q = 0; q < 4; ++q) {
                int Lc = lane * 4 + q;
                int P = Lc ^ (p & 15) ^ (lane & 7);
                *(bf16x4*)((char*)Gs + prow + (unsigned)P * 16 + kh * 8) =
                    cvt4(acc[i][j][4 * q + 0], acc[i][j][4 * q + 1],
                         acc[i][j][4 * q + 2], acc[i][j][4 * q + 3]);
            }
        }
    }
    __syncthreads();

    // ---------------- Phase B ----------------
    f32x16 oA, oB;
#pragma unroll
    for (int q = 0; q < 16; ++q) { oA[q] = 0.f; oB[q] = 0.f; }

    const int czl = w * 32 + lane;
    const bf16x8* wb = (const bf16x8*)WTf + ((size_t)kh * 128 + czl);
    const unsigned prow = (unsigned)lane * 2048;
    const int p15 = lane & 15;

#define LDG1(dst, kk) do { \
    int Lr = (kk) * 2 + kh; \
    int P = Lr ^ p15 ^ ((Lr >> 2) & 7); \
    dst = *(const bf16x8*)((const char*)Gs + prow + (unsigned)P * 16); } while (0)

    bf16x8 G0[8], G1[8], W0[8], W1[8], W2[8];
#define LDG8(Gg, kb) do { \
    LDG1(Gg[0], (kb) + 0); LDG1(Gg[1], (kb) + 1); LDG1(Gg[2], (kb) + 2); LDG1(Gg[3], (kb) + 3); \
    LDG1(Gg[4], (kb) + 4); LDG1(Gg[5], (kb) + 5); LDG1(Gg[6], (kb) + 6); LDG1(Gg[7], (kb) + 7); } while (0)
#define LDW8(Ww, kb) do { \
    Ww[0] = wb[((kb) + 0) * 256]; Ww[1] = wb[((kb) + 1) * 256]; \
    Ww[2] = wb[((kb) + 2) * 256]; Ww[3] = wb[((kb) + 3) * 256]; \
    Ww[4] = wb[((kb) + 4) * 256]; Ww[5] = wb[((kb) + 5) * 256]; \
    Ww[6] = wb[((kb) + 6) * 256]; Ww[7] = wb[((kb) + 7) * 256]; } while (0)
#define PH_B(Gg, Ww) do { \
    __builtin_amdgcn_s_setprio(1); \
    oA = MFMA(Gg[0], Ww[0], oA, 0, 0, 0); oB = MFMA(Gg[1], Ww[1], oB, 0, 0, 0); \
    oA = MFMA(Gg[2], Ww[2], oA, 0, 0, 0); oB = MFMA(Gg[3], Ww[3], oB, 0, 0, 0); \
    oA = MFMA(Gg[4], Ww[4], oA, 0, 0, 0); oB = MFMA(Gg[5], Ww[5], oB, 0, 0, 0); \
    oA = MFMA(Gg[6], Ww[6], oA, 0, 0, 0); oB = MFMA(Gg[7], Ww[7], oB, 0, 0, 0); \
    __builtin_amdgcn_s_setprio(0); } while (0)

    LDW8(W0, 0); LDW8(W1, 8); LDW8(W2, 16);
    LDG8(G0, 0); LDG8(G1, 8);
    PH_B(G0, W0); LDW8(W0, 24); LDG8(G0, 16);
    PH_B(G1, W1); LDW8(W1, 32); LDG8(G1, 24);
    PH_B(G0, W2); LDW8(W2, 40); LDG8(G0, 32);
    PH_B(G1, W0); LDW8(W0, 48); LDG8(G1, 40);
    PH_B(G0, W1); LDW8(W1, 56); LDG8(G0, 48);
    PH_B(G1, W2);                LDG8(G1, 56);
    PH_B(G0, W0);
    PH_B(G1, W1);

    f32x16 o = oA + oB;

#pragma unroll
    for (int reg = 0; reg < 16; ++reg) {
        int p = (reg & 3) + 8 * (reg >> 2) + 4 * kh;
        int pr = p >> 2, pt = p & 3;
        out[((size_t)(r0 + pr) * 256 + (t0 + pt)) * 128 + czl] = o[reg];
    }
}

extern "C" void kernel_launch(void* const* d_in, const int* in_sizes, int n_in,
                              void* d_out, int out_size, void* d_ws, size_t ws_size,
                              hipStream_t stream) {
    const float* msa = (const float*)d_in[0];
    const float* left = (const float*)d_in[1];
    const float* right = (const float*)d_in[2];
    const float* W = (const float*)d_in[3];

    __bf16* aTf = (__bf16*)d_ws;                        // 2 MB
    __bf16* bTf = aTf + (size_t)R * 4096;               // 2 MB
    __bf16* WTf = bTf + (size_t)R * 4096;               // 256 KB
    __bf16* WLRT = WTf + (size_t)128 * 1024;            // 32 KB
    float* outp = (float*)d_out;

    k_wt<<<512, 256, 0, stream>>>(W, WTf);
    k_wlr<<<64, 256, 0, stream>>>(left, right, WLRT);
    k_proj<<<256, 256, 0, stream>>>(msa, WLRT, aTf, bTf);
    k_main<<<dim3(32, 64), 256, 0, stream>>>(aTf, bTf, WTf, outp);
}

// Round 7
// 60.612 us; speedup vs baseline: 1.1404x; 1.1086x over previous
//
#include <hip/hip_runtime.h>

typedef __bf16 bf16x8 __attribute__((ext_vector_type(8)));
typedef __bf16 bf16x4 __attribute__((ext_vector_type(4)));
typedef float f32x16 __attribute__((ext_vector_type(16)));
typedef float f32x4 __attribute__((ext_vector_type(4)));

constexpr int S = 128, R = 256, CM = 256, C = 32, CZ = 128;

#define MFMA __builtin_amdgcn_mfma_f32_32x32x16_bf16

__device__ __forceinline__ bf16x4 cvt4(float a, float b, float c, float d) {
    bf16x4 r;
    r[0] = (__bf16)a; r[1] = (__bf16)b; r[2] = (__bf16)c; r[3] = (__bf16)d;
    return r;
}

// K0a: fragment-packed out_proj. k = e*32+c, WTf[((k>>3)*128+cz)*8 + (k&7)] = W[(c*32+e)*128+cz]
__global__ __launch_bounds__(256) void k_wt(const float* __restrict__ W,
                                            __bf16* __restrict__ WTf) {
    int g = blockIdx.x * 256 + threadIdx.x;
    int cz = g & 127;
    int k = g >> 7;
    int e = k >> 5, c = k & 31;
    float v = W[(size_t)(c * 32 + e) * 128 + cz];
    WTf[((size_t)(k >> 3) * 128 + cz) * 8 + (k & 7)] = (__bf16)v;
}

// K0b: WLRT[c][m], c<32 -> left[m][c], else right[m][c-32]
__global__ __launch_bounds__(256) void k_wlr(const float* __restrict__ Lp,
                                             const float* __restrict__ Rp,
                                             __bf16* __restrict__ WLRT) {
    int c = blockIdx.x;
    int m = threadIdx.x;
    const float* src = (c < 32) ? Lp : Rp;
    WLRT[(size_t)c * 256 + m] = (__bf16)src[(size_t)m * 32 + (c & 31)];
}

// K1: block (r, s-half). Stages 64 s-rows; 4 waves = (mi in {0,1}) x (side L/R).
// Writes fragment-packed aTf/bTf[r][ks][khf][c][8s].
__global__ __launch_bounds__(256) void k_proj(const float* __restrict__ msa,
                                              const __bf16* __restrict__ WLRT,
                                              __bf16* __restrict__ aTf,
                                              __bf16* __restrict__ bTf) {
    __shared__ __align__(16) __bf16 As[64 * 256];   // 32 KB
    const int r = blockIdx.x;
    const int sh = blockIdx.y;
    const int t = threadIdx.x;

#pragma unroll 4
    for (int it = 0; it < 16; ++it) {
        int idx = it * 256 + t;
        int row = idx >> 6;            // 0..63
        int cg = idx & 63;             // column group (4 floats)
        float4 v = *(const float4*)&msa[((size_t)(sh * 64 + row) * R + r) * CM + cg * 4];
        bf16x4 h = cvt4(v.x, v.y, v.z, v.w);
        int P = (cg >> 1) ^ (row & 15);
        *(bf16x4*)((char*)As + row * 512 + P * 16 + (cg & 1) * 8) = h;
    }
    __syncthreads();

    const int w = t >> 6;
    const int l31 = t & 31;
    const int kh = (t >> 5) & 1;
    const int sd = w & 1;              // 0 = left, 1 = right
    const int mi = w >> 1;             // s-tile within half

    f32x16 acc;
#pragma unroll
    for (int q = 0; q < 16; ++q) acc[q] = 0.f;

    const bf16x8* wb = (const bf16x8*)&WLRT[(size_t)(sd * 32 + l31) * 256 + 8 * kh];
    const int srow = mi * 32 + l31;
    const char* arow = (const char*)As + srow * 512;

    __builtin_amdgcn_s_setprio(1);
#pragma unroll
    for (int ks = 0; ks < 16; ++ks) {
        int P = (2 * ks + kh) ^ (srow & 15);
        bf16x8 af = *(const bf16x8*)(arow + P * 16);
        acc = MFMA(af, wb[2 * ks], acc, 0, 0, 0);
    }
    __builtin_amdgcn_s_setprio(0);

    __bf16* dst = sd ? bTf : aTf;
    const int wg = sh * 2 + mi;        // global 32-row group
#pragma unroll
    for (int q = 0; q < 4; ++q) {
        size_t base = (size_t)r * 4096 + (size_t)(2 * wg + (q >> 1)) * 512 +
                      (size_t)(q & 1) * 256 + (size_t)l31 * 8 + 4 * kh;
        *(bf16x4*)&dst[base] = cvt4(acc[4 * q + 0], acc[4 * q + 1],
                                    acc[4 * q + 2], acc[4 * q + 3]);
    }
}

// K2: 64 pairs (8r x 8t) per block, 8 waves / 512 thr, G in 128 KB LDS.
// Phase A: wave (rg=w>>1, tg=w&1) -> 2r x 4t sub-tile.
// Phase B: wave (kq=w>>1, ng=w&1): 2 M-tiles x 2 cz-slices over K-quarter,
// each W/G fragment feeds 4 MFMAs. 4-way K reduction via LDS (reuses G region).
__global__ __launch_bounds__(512, 2) void k_main(const __bf16* __restrict__ aTf,
                                                 const __bf16* __restrict__ bTf,
                                                 const __bf16* __restrict__ WTf,
                                                 float* __restrict__ out) {
    __shared__ __align__(16) __bf16 Gs[64 * 1024];   // 128 KB

    const int t = threadIdx.x;
    const int w = t >> 6;              // 0..7
    const int l = t & 63;
    const int lane = l & 31;
    const int kh = l >> 5;
    const int r0 = blockIdx.x * 8;
    const int t0 = blockIdx.y * 8;

    // ---------------- Phase A ----------------
    const int rg = w >> 1;             // 0..3
    const int tg = w & 1;              // 0..1

    f32x16 acc[2][4];
#pragma unroll
    for (int i = 0; i < 2; ++i)
#pragma unroll
        for (int j = 0; j < 4; ++j)
#pragma unroll
            for (int q = 0; q < 16; ++q) acc[i][j][q] = 0.f;

    const bf16x8* ap0 = (const bf16x8*)aTf + ((size_t)(r0 + 2 * rg + 0) * 512 + kh * 32 + lane);
    const bf16x8* ap1 = (const bf16x8*)aTf + ((size_t)(r0 + 2 * rg + 1) * 512 + kh * 32 + lane);
    const bf16x8* bp0 = (const bf16x8*)bTf + ((size_t)(t0 + 4 * tg + 0) * 512 + kh * 32 + lane);
    const bf16x8* bp1 = (const bf16x8*)bTf + ((size_t)(t0 + 4 * tg + 1) * 512 + kh * 32 + lane);
    const bf16x8* bp2 = (const bf16x8*)bTf + ((size_t)(t0 + 4 * tg + 2) * 512 + kh * 32 + lane);
    const bf16x8* bp3 = (const bf16x8*)bTf + ((size_t)(t0 + 4 * tg + 3) * 512 + kh * 32 + lane);

    bf16x8 A0[2], B0[4], A1[2], B1[4];
#define LDA(Aa, Bb, ks) do { \
    Aa[0] = ap0[(ks) * 64]; Aa[1] = ap1[(ks) * 64]; \
    Bb[0] = bp0[(ks) * 64]; Bb[1] = bp1[(ks) * 64]; \
    Bb[2] = bp2[(ks) * 64]; Bb[3] = bp3[(ks) * 64]; } while (0)
#define PH_A(Aa, Bb) do { \
    __builtin_amdgcn_s_setprio(1); \
    acc[0][0] = MFMA(Aa[0], Bb[0], acc[0][0], 0, 0, 0); \
    acc[0][1] = MFMA(Aa[0], Bb[1], acc[0][1], 0, 0, 0); \
    acc[0][2] = MFMA(Aa[0], Bb[2], acc[0][2], 0, 0, 0); \
    acc[0][3] = MFMA(Aa[0], Bb[3], acc[0][3], 0, 0, 0); \
    acc[1][0] = MFMA(Aa[1], Bb[0], acc[1][0], 0, 0, 0); \
    acc[1][1] = MFMA(Aa[1], Bb[1], acc[1][1], 0, 0, 0); \
    acc[1][2] = MFMA(Aa[1], Bb[2], acc[1][2], 0, 0, 0); \
    acc[1][3] = MFMA(Aa[1], Bb[3], acc[1][3], 0, 0, 0); \
    __builtin_amdgcn_s_setprio(0); } while (0)

    LDA(A0, B0, 0);
#pragma unroll
    for (int ks = 0; ks < 8; ks += 2) {
        LDA(A1, B1, ks + 1);
        PH_A(A0, B0);
        LDA(A0, B0, (ks + 2) & 7);
        PH_A(A1, B1);
    }

    // G -> LDS, row p = rlocal*8 + tlocal (2048 B), chunk swizzle
#pragma unroll
    for (int i = 0; i < 2; ++i) {
#pragma unroll
        for (int j = 0; j < 4; ++j) {
            int p = (2 * rg + i) * 8 + 4 * tg + j;
            unsigned prow = (unsigned)p * 2048;
#pragma unroll
            for (int q = 0; q < 4; ++q) {
                int Lc = lane * 4 + q;
                int P = Lc ^ (p & 15) ^ (lane & 7);
                *(bf16x4*)((char*)Gs + prow + (unsigned)P * 16 + kh * 8) =
                    cvt4(acc[i][j][4 * q + 0], acc[i][j][4 * q + 1],
                         acc[i][j][4 * q + 2], acc[i][j][4 * q + 3]);
            }
        }
    }
    __syncthreads();

    // ---------------- Phase B ----------------
    const int kq = w >> 1;             // K-quarter 0..3
    const int ng = w & 1;              // cz-slice group (2 slices each)
    const int czl0 = ng * 64 + lane;
    const int czl1 = czl0 + 32;
    const bf16x8* wb0 = (const bf16x8*)WTf + ((size_t)kh * 128 + czl0);
    const bf16x8* wb1 = (const bf16x8*)WTf + ((size_t)kh * 128 + czl1);
    const unsigned prow0 = (unsigned)lane * 2048;
    const unsigned prow1 = (unsigned)(lane + 32) * 2048;
    const int p15 = lane & 15;

    f32x16 o00, o01, o10, o11;
#pragma unroll
    for (int q = 0; q < 16; ++q) { o00[q] = 0.f; o01[q] = 0.f; o10[q] = 0.f; o11[q] = 0.f; }

    bf16x8 Wa0, Wa1, Ga0, Ga1, Wb0_, Wb1_, Gb0, Gb1;
#define LDB(W0v, W1v, G0v, G1v, kk) do { \
    W0v = wb0[(size_t)(kk) * 256]; \
    W1v = wb1[(size_t)(kk) * 256]; \
    int Lr = (kk) * 2 + kh; \
    int P = Lr ^ p15 ^ ((Lr >> 2) & 7); \
    G0v = *(const bf16x8*)((const char*)Gs + prow0 + (unsigned)P * 16); \
    G1v = *(const bf16x8*)((const char*)Gs + prow1 + (unsigned)P * 16); } while (0)
#define PHB(W0v, W1v, G0v, G1v) do { \
    __builtin_amdgcn_s_setprio(1); \
    o00 = MFMA(G0v, W0v, o00, 0, 0, 0); \
    o01 = MFMA(G0v, W1v, o01, 0, 0, 0); \
    o10 = MFMA(G1v, W0v, o10, 0, 0, 0); \
    o11 = MFMA(G1v, W1v, o11, 0, 0, 0); \
    __builtin_amdgcn_s_setprio(0); } while (0)

    LDB(Wa0, Wa1, Ga0, Ga1, kq * 16);
#pragma unroll
    for (int j = 0; j < 16; j += 2) {
        LDB(Wb0_, Wb1_, Gb0, Gb1, kq * 16 + ((j + 1) & 15));
        PHB(Wa0, Wa1, Ga0, Ga1);
        LDB(Wa0, Wa1, Ga0, Ga1, kq * 16 + ((j + 2) & 15));
        PHB(Wb0_, Wb1_, Gb0, Gb1);
    }
    __syncthreads();   // G region dead; safe to overwrite with partials

    // partials: region w*16KB, layout [s][piece][l] x 16B, s = mi*2+ni
    {
        char* pr = (char*)Gs + (size_t)w * 16384;
        const f32x16* os[4] = {&o00, &o01, &o10, &o11};
#pragma unroll
        for (int s2 = 0; s2 < 4; ++s2) {
#pragma unroll
            for (int pc = 0; pc < 4; ++pc) {
                f32x4 v;
                v[0] = (*os[s2])[4 * pc + 0]; v[1] = (*os[s2])[4 * pc + 1];
                v[2] = (*os[s2])[4 * pc + 2]; v[3] = (*os[s2])[4 * pc + 3];
                *(f32x4*)(pr + ((s2 * 4 + pc) * 64 + l) * 16) = v;
            }
        }
    }
    __syncthreads();

    // reduce over K-quarters: thread (w,l): ngx = w>>2, mix = (w>>1)&1, nix = w&1
    {
        const int ngx = w >> 2;
        const int mix = (w >> 1) & 1;
        const int nix = w & 1;
        const int s2 = mix * 2 + nix;
        f32x16 sm;
#pragma unroll
        for (int q = 0; q < 16; ++q) sm[q] = 0.f;
#pragma unroll
        for (int kq2 = 0; kq2 < 4; ++kq2) {
            const char* pr = (const char*)Gs + (size_t)(kq2 * 2 + ngx) * 16384;
#pragma unroll
            for (int pc = 0; pc < 4; ++pc) {
                f32x4 v = *(const f32x4*)(pr + ((s2 * 4 + pc) * 64 + l) * 16);
                sm[4 * pc + 0] += v[0]; sm[4 * pc + 1] += v[1];
                sm[4 * pc + 2] += v[2]; sm[4 * pc + 3] += v[3];
            }
        }
        const int czl = ngx * 64 + nix * 32 + (l & 31);
        const int khx = l >> 5;
#pragma unroll
        for (int reg = 0; reg < 16; ++reg) {
            int pl = mix * 32 + (reg & 3) + 8 * (reg >> 2) + 4 * khx;
            int prr = pl >> 3, ptt = pl & 7;
            out[((size_t)(r0 + prr) * 256 + (t0 + ptt)) * 128 + czl] = sm[reg];
        }
    }
}

extern "C" void kernel_launch(void* const* d_in, const int* in_sizes, int n_in,
                              void* d_out, int out_size, void* d_ws, size_t ws_size,
                              hipStream_t stream) {
    const float* msa = (const float*)d_in[0];
    const float* left = (const float*)d_in[1];
    const float* right = (const float*)d_in[2];
    const float* W = (const float*)d_in[3];

    __bf16* aTf = (__bf16*)d_ws;                        // 2 MB
    __bf16* bTf = aTf + (size_t)R * 4096;               // 2 MB
    __bf16* WTf = bTf + (size_t)R * 4096;               // 256 KB
    __bf16* WLRT = WTf + (size_t)128 * 1024;            // 32 KB
    float* outp = (float*)d_out;

    k_wt<<<512, 256, 0, stream>>>(W, WTf);
    k_wlr<<<64, 256, 0, stream>>>(left, right, WLRT);
    k_proj<<<dim3(256, 2), 256, 0, stream>>>(msa, WLRT, aTf, bTf);
    k_main<<<dim3(32, 32), 512, 0, stream>>>(aTf, bTf, WTf, outp);
}